// Round 1
// baseline (256.100 us; speedup 1.0000x reference)
//
#include <hip/hip_runtime.h>
#include <stdint.h>

#define TOKENS 4096
#define INF    4096
#define OUTF   4096
#define LRK    256
#define ACT    5

typedef __bf16 bf16x8 __attribute__((ext_vector_type(8)));
typedef float  f32x4  __attribute__((ext_vector_type(4)));
typedef unsigned short u16x8 __attribute__((ext_vector_type(8)));

typedef __attribute__((address_space(3))) void lds_void;
typedef __attribute__((address_space(1))) const void gbl_cvoid;

__device__ __forceinline__ unsigned short f2bf(float f) {
  union { float f; uint32_t u; } v; v.f = f;
  return (unsigned short)((v.u + 0x7FFFu + ((v.u >> 16) & 1u)) >> 16);
}

// ---------------- prep: f32 -> bf16 (vectorized) ----------------
__global__ void cvt_bf16_kernel(const float* __restrict__ in,
                                u16x8* __restrict__ out, int n8) {
  int i = blockIdx.x * blockDim.x + threadIdx.x;
  int stride = gridDim.x * blockDim.x;
  for (; i < n8; i += stride) {
    const f32x4* p = (const f32x4*)in + (size_t)i * 2;
    f32x4 a = p[0], b = p[1];
    u16x8 o;
    o[0]=f2bf(a[0]); o[1]=f2bf(a[1]); o[2]=f2bf(a[2]); o[3]=f2bf(a[3]);
    o[4]=f2bf(b[0]); o[5]=f2bf(b[1]); o[6]=f2bf(b[2]); o[7]=f2bf(b[3]);
    out[i] = o;
  }
}

// ---------------- prep: gather butterfly effective weights ----------------
// weff[ob][s][r][c] = weight[q*256 + (256*j + r)/5][(256*j + r)%5][c],
//   where f = flat[ob*5+s], q = f/5, j = f%5.
__global__ void build_weff_kernel(const float* __restrict__ weight,
                                  const int* __restrict__ flat,
                                  unsigned short* __restrict__ weff) {
  int row = blockIdx.x;                 // ob*1280 + s*256 + r, 20480 rows
  int ob = row / 1280;
  int t  = row - ob * 1280;
  int s  = t >> 8;
  int r  = t & 255;
  int f  = flat[ob * ACT + s];
  int q  = f / ACT;
  int jj = f - q * ACT;
  int k  = (jj << 8) + r;
  int i  = k / ACT;
  int a  = k - i * ACT;
  const float* src = weight + ((size_t)((q << 8) + i) * ACT + a) * 256;
  weff[(size_t)row * 256 + threadIdx.x] = f2bf(src[threadIdx.x]);
}

// ---------------- t1 = x @ w1^T  (M=4096, N=256, K=4096), bf16 out -------
// 64x64 tile, BK=64, 4 waves (2x2), each wave 32x32 = 2x2 mfma frags.
__global__ __launch_bounds__(256) void t1_gemm_kernel(
    const unsigned short* __restrict__ xb,
    const unsigned short* __restrict__ w1b,
    unsigned short* __restrict__ t1) {
  __shared__ __align__(16) unsigned short smem[64*64 + 64*64];
  const int tid  = threadIdx.x;
  const int lane = tid & 63;
  const int w    = tid >> 6;
  const int wm   = (w >> 1) * 32, wn = (w & 1) * 32;
  const int lr   = lane & 15,  lk = lane >> 4;
  const int row0 = blockIdx.x * 64;
  const int col0 = blockIdx.y * 64;

  f32x4 acc[2][2];
#pragma unroll
  for (int m = 0; m < 2; ++m)
#pragma unroll
    for (int n = 0; n < 2; ++n) acc[m][n] = (f32x4){0.f, 0.f, 0.f, 0.f};

  const unsigned short* Ab = xb  + (size_t)row0 * INF;
  const unsigned short* Bb = w1b + (size_t)col0 * INF;

  for (int k0 = 0; k0 < INF; k0 += 64) {
    __syncthreads();
    // stage A(64x64) and B(64x64): 512 16B-chunks each, swizzled source,
    // linear LDS dest (global_load_lds requirement).
#pragma unroll
    for (int it = 0; it < 2; ++it) {
      int chunk = it * 256 + tid;
      int r = chunk >> 3, c = chunk & 7;
      int csw = c ^ (r & 7);
      const unsigned short* srcA = Ab + (size_t)r * INF + k0 + csw * 8;
      __builtin_amdgcn_global_load_lds((gbl_cvoid*)srcA,
          (lds_void*)&smem[chunk * 8], 16, 0, 0);
      const unsigned short* srcB = Bb + (size_t)r * INF + k0 + csw * 8;
      __builtin_amdgcn_global_load_lds((gbl_cvoid*)srcB,
          (lds_void*)&smem[4096 + chunk * 8], 16, 0, 0);
    }
    __syncthreads();
#pragma unroll
    for (int kk = 0; kk < 2; ++kk) {
      bf16x8 af[2], bfr[2];
#pragma unroll
      for (int m = 0; m < 2; ++m) {
        int r = wm + m * 16 + lr;
        int ch = (kk * 4 + lk) ^ (r & 7);
        af[m] = *(const bf16x8*)&smem[r * 64 + ch * 8];
      }
#pragma unroll
      for (int n = 0; n < 2; ++n) {
        int r = wn + n * 16 + lr;
        int ch = (kk * 4 + lk) ^ (r & 7);
        bfr[n] = *(const bf16x8*)&smem[4096 + r * 64 + ch * 8];
      }
#pragma unroll
      for (int m = 0; m < 2; ++m)
#pragma unroll
        for (int n = 0; n < 2; ++n)
          acc[m][n] = __builtin_amdgcn_mfma_f32_16x16x32_bf16(
              af[m], bfr[n], acc[m][n], 0, 0, 0);
    }
  }
#pragma unroll
  for (int m = 0; m < 2; ++m)
#pragma unroll
    for (int n = 0; n < 2; ++n) {
      int col = col0 + wn + n * 16 + lr;
      int row = row0 + wm + m * 16 + lk * 4;
#pragma unroll
      for (int j = 0; j < 4; ++j)
        t1[(size_t)(row + j) * LRK + col] = f2bf(acc[m][n][j]);
    }
}

// ---------------- main: out = t1@w2^T + b + butterfly ----------------
// Per 128x128 tile: 6 K-panels (lowrank + 5 butterfly blocks), each K=256.
__global__ __launch_bounds__(256) void main_gemm_kernel(
    const unsigned short* __restrict__ xb,
    const unsigned short* __restrict__ t1,
    const unsigned short* __restrict__ w2b,
    const unsigned short* __restrict__ weff,
    const int* __restrict__ flat,
    const float* __restrict__ bias,
    float* __restrict__ out) {
  __shared__ __align__(16) unsigned short smem[128*64 + 128*64]; // A | B, 32 KiB
  const int tid  = threadIdx.x;
  const int lane = tid & 63;
  const int w    = tid >> 6;
  const int wm   = (w >> 1) * 64, wn = (w & 1) * 64;
  const int lr   = lane & 15,  lk = lane >> 4;
  const int row0 = blockIdx.x * 128;
  const int col0 = blockIdx.y * 128;
  const int ob   = blockIdx.y >> 1;

  f32x4 acc[4][4];
#pragma unroll
  for (int m = 0; m < 4; ++m)
#pragma unroll
    for (int n = 0; n < 4; ++n) acc[m][n] = (f32x4){0.f, 0.f, 0.f, 0.f};

  for (int s = 0; s < 6; ++s) {
    const unsigned short* Ab;
    const unsigned short* Bb;
    int Astr;
    if (s == 0) {
      Ab = t1 + (size_t)row0 * LRK;  Astr = LRK;
      Bb = w2b + (size_t)col0 * LRK;                 // stride 256
    } else {
      int f = flat[ob * ACT + s - 1];
      int q = f / ACT;
      Ab = xb + (size_t)row0 * INF + q * 256;  Astr = INF;
      Bb = weff + ((size_t)(ob * ACT + s - 1) * 256 + (col0 & 255)) * 256;
    }
    for (int ks = 0; ks < 4; ++ks) {
      int k0 = ks * 64;
      __syncthreads();
#pragma unroll
      for (int it = 0; it < 4; ++it) {
        int chunk = it * 256 + tid;           // 1024 chunks per tile
        int r = chunk >> 3, c = chunk & 7;
        int csw = c ^ (r & 7);
        const unsigned short* srcA = Ab + (size_t)r * Astr + k0 + csw * 8;
        __builtin_amdgcn_global_load_lds((gbl_cvoid*)srcA,
            (lds_void*)&smem[chunk * 8], 16, 0, 0);
        const unsigned short* srcB = Bb + (size_t)r * 256 + k0 + csw * 8;
        __builtin_amdgcn_global_load_lds((gbl_cvoid*)srcB,
            (lds_void*)&smem[8192 + chunk * 8], 16, 0, 0);
      }
      __syncthreads();
#pragma unroll
      for (int kk = 0; kk < 2; ++kk) {
        bf16x8 af[4], bfr[4];
#pragma unroll
        for (int m = 0; m < 4; ++m) {
          int r = wm + m * 16 + lr;
          int ch = (kk * 4 + lk) ^ (r & 7);
          af[m] = *(const bf16x8*)&smem[r * 64 + ch * 8];
        }
#pragma unroll
        for (int n = 0; n < 4; ++n) {
          int r = wn + n * 16 + lr;
          int ch = (kk * 4 + lk) ^ (r & 7);
          bfr[n] = *(const bf16x8*)&smem[8192 + r * 64 + ch * 8];
        }
#pragma unroll
        for (int m = 0; m < 4; ++m)
#pragma unroll
          for (int n = 0; n < 4; ++n)
            acc[m][n] = __builtin_amdgcn_mfma_f32_16x16x32_bf16(
                af[m], bfr[n], acc[m][n], 0, 0, 0);
      }
    }
  }
  // epilogue: += bias, f32 store
#pragma unroll
  for (int n = 0; n < 4; ++n) {
    int col = col0 + wn + n * 16 + lr;
    float bv = bias[col];
#pragma unroll
    for (int m = 0; m < 4; ++m) {
      int row = row0 + wm + m * 16 + lk * 4;
#pragma unroll
      for (int j = 0; j < 4; ++j)
        out[(size_t)(row + j) * OUTF + col] = acc[m][n][j] + bv;
    }
  }
}

extern "C" void kernel_launch(void* const* d_in, const int* in_sizes, int n_in,
                              void* d_out, int out_size, void* d_ws, size_t ws_size,
                              hipStream_t stream) {
  const float* x      = (const float*)d_in[0];
  const float* weight = (const float*)d_in[1];
  const float* w1     = (const float*)d_in[2];
  const float* w2     = (const float*)d_in[3];
  const float* b      = (const float*)d_in[4];
  const int*   flat   = (const int*)d_in[5];
  float* out = (float*)d_out;

  char* ws = (char*)d_ws;
  unsigned short* xb   = (unsigned short*)(ws);                  // 32 MiB
  unsigned short* w1b  = (unsigned short*)(ws + 33554432);       // 2 MiB
  unsigned short* w2b  = (unsigned short*)(ws + 35651584);       // 2 MiB
  unsigned short* t1   = (unsigned short*)(ws + 37748736);       // 2 MiB
  unsigned short* weff = (unsigned short*)(ws + 39845888);       // 10 MiB

  cvt_bf16_kernel<<<2048, 256, 0, stream>>>(x,  (u16x8*)xb,  (4096*4096)/8);
  cvt_bf16_kernel<<<512,  256, 0, stream>>>(w1, (u16x8*)w1b, (256*4096)/8);
  cvt_bf16_kernel<<<512,  256, 0, stream>>>(w2, (u16x8*)w2b, (4096*256)/8);
  build_weff_kernel<<<20480, 256, 0, stream>>>(weight, flat, weff);
  t1_gemm_kernel<<<dim3(64, 4), 256, 0, stream>>>(xb, w1b, t1);
  main_gemm_kernel<<<dim3(32, 32), 256, 0, stream>>>(xb, t1, w2b, weff, flat, b, out);
}

// Round 3
// 253.492 us; speedup vs baseline: 1.0103x; 1.0103x over previous
//
#include <hip/hip_runtime.h>
#include <stdint.h>

typedef __bf16 bf16x8 __attribute__((ext_vector_type(8)));
typedef float  f32x4  __attribute__((ext_vector_type(4)));
typedef unsigned short u16x8 __attribute__((ext_vector_type(8)));
typedef unsigned short u16x4 __attribute__((ext_vector_type(4)));

typedef __attribute__((address_space(3))) void lds_void;
typedef __attribute__((address_space(1))) const void gbl_cvoid;

__device__ __forceinline__ unsigned short f2bf(float f) {
  union { float f; uint32_t u; } v; v.f = f;
  return (unsigned short)((v.u + 0x7FFFu + ((v.u >> 16) & 1u)) >> 16);
}

// ---------------- prep: fused f32 -> bf16 for x (strided into xbex), w1, w2 --
__global__ void cvt_all_kernel(const float* __restrict__ x,
                               const float* __restrict__ w1,
                               const float* __restrict__ w2,
                               unsigned short* __restrict__ xbex,
                               unsigned short* __restrict__ w1b,
                               unsigned short* __restrict__ w2b) {
  const int NX = (4096 * 4096) / 8;
  const int NW = (256 * 4096) / 8;
  const int total = NX + 2 * NW;
  for (int i = blockIdx.x * 256 + threadIdx.x; i < total; i += gridDim.x * 256) {
    const float* src;
    unsigned short* dst;
    if (i < NX) {
      int row = i >> 9, c = i & 511;
      src = x + (size_t)i * 8;
      dst = xbex + (size_t)row * 4352 + c * 8;
    } else if (i < NX + NW) {
      int k = i - NX;
      src = w1 + (size_t)k * 8;
      dst = w1b + (size_t)k * 8;
    } else {
      int k = i - NX - NW;
      src = w2 + (size_t)k * 8;
      dst = w2b + (size_t)k * 8;
    }
    f32x4 a = ((const f32x4*)src)[0], bb = ((const f32x4*)src)[1];
    u16x8 o;
    o[0] = f2bf(a[0]); o[1] = f2bf(a[1]); o[2] = f2bf(a[2]); o[3] = f2bf(a[3]);
    o[4] = f2bf(bb[0]); o[5] = f2bf(bb[1]); o[6] = f2bf(bb[2]); o[7] = f2bf(bb[3]);
    *(u16x8*)dst = o;
  }
}

// ---------------- prep: gather butterfly effective weights (vectorized) ------
__global__ void build_weff_kernel(const float* __restrict__ weight,
                                  const int* __restrict__ flat,
                                  unsigned short* __restrict__ weff) {
  int gid = blockIdx.x * 256 + threadIdx.x;   // 1,310,720 total
  int row = gid >> 6;                          // 0..20479
  int c4  = (gid & 63) << 2;
  int ob = row / 1280;
  int t  = row - ob * 1280;
  int s  = t >> 8;
  int r  = t & 255;
  int f  = flat[ob * 5 + s];
  int q  = f / 5;
  int jj = f - q * 5;
  int k  = (jj << 8) + r;
  int i2 = k / 5;
  int a  = k - i2 * 5;
  const float* src = weight + ((size_t)((q << 8) + i2) * 5 + a) * 256 + c4;
  f32x4 v = *(const f32x4*)src;
  u16x4 o;
  o[0] = f2bf(v[0]); o[1] = f2bf(v[1]); o[2] = f2bf(v[2]); o[3] = f2bf(v[3]);
  *(u16x4*)(weff + (size_t)row * 256 + c4) = o;
}

// ---------------- t1 = x @ w1^T, split-K x2, 2-phase prefetch ----------------
__global__ __launch_bounds__(256) void t1_gemm_kernel(
    const unsigned short* __restrict__ xbex,
    const unsigned short* __restrict__ w1b,
    float* __restrict__ t1p) {
  __shared__ __align__(16) char smem[32768];  // dbuf x (A 8K + B 8K)
  const int tid = threadIdx.x, lane = tid & 63, w = tid >> 6;
  const int wr = w >> 1, wc = w & 1;
  const int lr = lane & 15, lk = lane >> 4, lr7 = lr & 7;
  const int row0 = blockIdx.x << 6, col0 = blockIdx.y << 6;
  const int z = blockIdx.z;
  const int rr = tid >> 3;
  const int csw = (tid & 7) ^ (rr & 7);
  const int cs0 = (lk ^ lr7) << 4, cs1 = ((4 | lk) ^ lr7) << 4;
  const int aRow = ((wr << 5) + lr) << 7;
  const int bRow = ((wc << 5) + lr) << 7;

  const unsigned short* As = xbex + (size_t)(row0 + rr) * 4352 + (z << 11) + csw * 8;
  const unsigned short* Bs = w1b + (size_t)(col0 + rr) * 4096 + (z << 11) + csw * 8;

  f32x4 acc[2][2];
#pragma unroll
  for (int m = 0; m < 2; ++m)
#pragma unroll
    for (int n = 0; n < 2; ++n) acc[m][n] = (f32x4){0.f, 0.f, 0.f, 0.f};

  auto STAGE = [&](int t) {
    char* d = smem + ((t & 1) << 14) + (tid << 4);
    const unsigned short* a = As + (t << 6);
    const unsigned short* bp = Bs + (t << 6);
    __builtin_amdgcn_global_load_lds((gbl_cvoid*)a, (lds_void*)d, 16, 0, 0);
    __builtin_amdgcn_global_load_lds((gbl_cvoid*)(a + (size_t)32 * 4352), (lds_void*)(d + 4096), 16, 0, 0);
    __builtin_amdgcn_global_load_lds((gbl_cvoid*)bp, (lds_void*)(d + 8192), 16, 0, 0);
    __builtin_amdgcn_global_load_lds((gbl_cvoid*)(bp + (size_t)32 * 4096), (lds_void*)(d + 12288), 16, 0, 0);
  };

  STAGE(0);
  asm volatile("s_waitcnt vmcnt(0)" ::: "memory");
  __builtin_amdgcn_s_barrier();
#pragma unroll 1
  for (int t = 0; t < 32; ++t) {
    if (t < 31) STAGE(t + 1);
    const char* Ab = smem + ((t & 1) << 14);
    const char* Bb = Ab + 8192;
    bf16x8 aq[2][2], bq[2][2];
#pragma unroll
    for (int m = 0; m < 2; ++m) {
      aq[m][0] = *(const bf16x8*)(Ab + aRow + m * 2048 + cs0);
      aq[m][1] = *(const bf16x8*)(Ab + aRow + m * 2048 + cs1);
      bq[m][0] = *(const bf16x8*)(Bb + bRow + m * 2048 + cs0);
      bq[m][1] = *(const bf16x8*)(Bb + bRow + m * 2048 + cs1);
    }
#pragma unroll
    for (int m = 0; m < 2; ++m)
#pragma unroll
      for (int n = 0; n < 2; ++n) {
        acc[m][n] = __builtin_amdgcn_mfma_f32_16x16x32_bf16(aq[m][0], bq[n][0], acc[m][n], 0, 0, 0);
        acc[m][n] = __builtin_amdgcn_mfma_f32_16x16x32_bf16(aq[m][1], bq[n][1], acc[m][n], 0, 0, 0);
      }
    if (t < 31) {
      asm volatile("s_waitcnt vmcnt(0)" ::: "memory");
      __builtin_amdgcn_s_barrier();
    }
  }
#pragma unroll
  for (int m = 0; m < 2; ++m)
#pragma unroll
    for (int n = 0; n < 2; ++n) {
      int row = row0 + (wr << 5) + (m << 4) + (lk << 2);
      int col = col0 + (wc << 5) + (n << 4) + lr;
#pragma unroll
      for (int jj = 0; jj < 4; ++jj)
        t1p[((size_t)z << 20) + (size_t)(row + jj) * 256 + col] = acc[m][n][jj];
    }
}

// ---------------- reduce split-K partials -> bf16 into xbex cols 4096+ -------
__global__ void t1_reduce_kernel(const float* __restrict__ t1p,
                                 unsigned short* __restrict__ xbex) {
  int i = blockIdx.x * 256 + threadIdx.x;   // 1M
  float s = t1p[i] + t1p[i + (1 << 20)];
  int row = i >> 8, col = i & 255;
  xbex[(size_t)row * 4352 + 4096 + col] = f2bf(s);
}

// ---------------- main: 256x256 tile, 4-phase groups, counted vmcnt ----------
// A = xbex [4096][4352] (cols 0..4095 = x, 4096.. = t1). 6 K-panels of 256
// -> 24 K-tiles (BK=64), double-buffered (buf = tile&1).
// Safe stage schedule per group(t): ph0/1 stage A-halves of t+1 (other buf,
// never read this group); ph2/3 stage B-halves of t+2 (this buf, B-old fully
// consumed in ph0, >=2 barriers earlier). vmcnt(4) at group end => tile t+1
// fully landed, B(t+2)'s 4 loads stay in flight.
__global__ __launch_bounds__(512, 2) void main_gemm_kernel(
    const unsigned short* __restrict__ xbex,
    const unsigned short* __restrict__ w2all,
    const int* __restrict__ flat,
    const float* __restrict__ bias,
    float* __restrict__ out) {
  __shared__ __align__(16) char smem[131072];  // 2 bufs x (A 32K + B 32K)
  const int tid  = threadIdx.x;
  const int lane = tid & 63;
  const int w    = tid >> 6;
  const int wr   = w >> 2, wc = w & 3;
  const int lr   = lane & 15, lk = lane >> 4, lr7 = lr & 7;

  int bid = blockIdx.x;
  int swz = ((bid & 7) << 5) | (bid >> 3);      // bijective: 256 % 8 == 0
  const int bx = swz & 15, by = swz >> 4;
  const int row0 = bx << 8, col0 = by << 8;

  const int cs0 = (lk ^ lr7) << 4;
  const int cs1 = ((4 | lk) ^ lr7) << 4;
  const int aRow = (((wr << 7) + lr)) << 7;     // (wr*128+lr)*128 bytes
  const int bRow = (((wc << 6) + lr)) << 7;     // (wc*64+lr)*128 bytes

  const int rr0 = tid >> 3;                     // 0..63
  const int csw = (tid & 7) ^ (rr0 & 7);

  const int base5 = by * 5;
  const int cA1 = (flat[base5 + 0] / 5) << 8;
  const int cA2 = (flat[base5 + 1] / 5) << 8;
  const int cA3 = (flat[base5 + 2] / 5) << 8;
  const int cA4 = (flat[base5 + 3] / 5) << 8;
  const int cA5 = (flat[base5 + 4] / 5) << 8;

  const unsigned short* xbA = xbex + (size_t)row0 * 4352;

  f32x4 acc[8][4];
#pragma unroll
  for (int m = 0; m < 8; ++m)
#pragma unroll
    for (int n = 0; n < 4; ++n) acc[m][n] = (f32x4){0.f, 0.f, 0.f, 0.f};

  // stage A half h (rows h*128..h*128+127) of K-tile tt into buf (tt&1)
  auto stage_A = [&](int tt, int h) {
    int s = tt >> 2, k0 = (tt & 3) << 6;
    char* dst = smem + ((tt & 1) << 16) + (h << 14) + (tid << 4);
    int colA = (s == 0) ? 4096 : (s == 1) ? cA1 : (s == 2) ? cA2
             : (s == 3) ? cA3 : (s == 4) ? cA4 : cA5;
    const unsigned short* src = xbA + (size_t)((h << 7) + rr0) * 4352 + colA + k0 + csw * 8;
    __builtin_amdgcn_global_load_lds((gbl_cvoid*)src, (lds_void*)dst, 16, 0, 0);
    __builtin_amdgcn_global_load_lds((gbl_cvoid*)(src + (size_t)64 * 4352),
                                     (lds_void*)(dst + 8192), 16, 0, 0);
  };
  // stage B half h of K-tile tt into buf (tt&1)
  auto stage_B = [&](int tt, int h) {
    int s = tt >> 2, k0 = (tt & 3) << 6;
    char* dst = smem + ((tt & 1) << 16) + 32768 + (h << 14) + (tid << 4);
    int pidx = (s == 0) ? by : (16 + base5 + (s - 1));
    const unsigned short* src = w2all + ((size_t)pidx << 16)
                              + ((h << 7) + rr0) * 256 + k0 + csw * 8;
    __builtin_amdgcn_global_load_lds((gbl_cvoid*)src, (lds_void*)dst, 16, 0, 0);
    __builtin_amdgcn_global_load_lds((gbl_cvoid*)(src + 64 * 256),
                                     (lds_void*)(dst + 8192), 16, 0, 0);
  };

  // compute tile t from buf(t&1); optionally stage A(t+1), B(t+2); close vmcnt
  auto do_group = [&](int t, bool stA, bool stB, int vm) {
    const char* Ab = smem + ((t & 1) << 16);
    const char* Bb = Ab + 32768;
    bf16x8 bq[4][2];
#pragma unroll
    for (int n = 0; n < 4; ++n) {
      bq[n][0] = *(const bf16x8*)(Bb + bRow + n * 2048 + cs0);
      bq[n][1] = *(const bf16x8*)(Bb + bRow + n * 2048 + cs1);
    }
#pragma unroll
    for (int j = 0; j < 4; ++j) {
      bf16x8 aq[2][2];
#pragma unroll
      for (int mm = 0; mm < 2; ++mm) {
        aq[mm][0] = *(const bf16x8*)(Ab + aRow + (j * 2 + mm) * 2048 + cs0);
        aq[mm][1] = *(const bf16x8*)(Ab + aRow + (j * 2 + mm) * 2048 + cs1);
      }
      if (j == 0 && stA) stage_A(t + 1, 0);
      if (j == 1 && stA) stage_A(t + 1, 1);
      if (j == 2 && stB) stage_B(t + 2, 0);
      if (j == 3 && stB) stage_B(t + 2, 1);
      __builtin_amdgcn_s_barrier();
      __builtin_amdgcn_s_setprio(1);
#pragma unroll
      for (int mm = 0; mm < 2; ++mm)
#pragma unroll
        for (int n = 0; n < 4; ++n) {
          acc[j * 2 + mm][n] = __builtin_amdgcn_mfma_f32_16x16x32_bf16(
              aq[mm][0], bq[n][0], acc[j * 2 + mm][n], 0, 0, 0);
          acc[j * 2 + mm][n] = __builtin_amdgcn_mfma_f32_16x16x32_bf16(
              aq[mm][1], bq[n][1], acc[j * 2 + mm][n], 0, 0, 0);
        }
      __builtin_amdgcn_s_setprio(0);
      if (j == 3) {
        if (vm == 4)      asm volatile("s_waitcnt vmcnt(4)" ::: "memory");
        else if (vm == 0) asm volatile("s_waitcnt vmcnt(0)" ::: "memory");
      }
      __builtin_amdgcn_s_barrier();
    }
  };

  // prologue: tile0 (A+B) + B of tile1; vmcnt(4) => tile0 landed
  stage_A(0, 0); stage_A(0, 1);
  stage_B(0, 0); stage_B(0, 1);
  stage_B(1, 0); stage_B(1, 1);
  asm volatile("s_waitcnt vmcnt(4)" ::: "memory");
  __builtin_amdgcn_s_barrier();

#pragma unroll 1
  for (int t = 0; t < 22; ++t) do_group(t, true, true, 4);
  do_group(22, true, false, 0);
  do_group(23, false, false, -1);

  // epilogue: + bias, f32 store
#pragma unroll
  for (int n = 0; n < 4; ++n) {
    int col = col0 + (wc << 6) + (n << 4) + lr;
    float bv = bias[col];
#pragma unroll
    for (int m = 0; m < 8; ++m) {
      int row = row0 + (wr << 7) + (m << 4) + (lk << 2);
#pragma unroll
      for (int jj = 0; jj < 4; ++jj)
        out[(size_t)(row + jj) * 4096 + col] = acc[m][n][jj] + bv;
    }
  }
}

extern "C" void kernel_launch(void* const* d_in, const int* in_sizes, int n_in,
                              void* d_out, int out_size, void* d_ws, size_t ws_size,
                              hipStream_t stream) {
  const float* x      = (const float*)d_in[0];
  const float* weight = (const float*)d_in[1];
  const float* w1     = (const float*)d_in[2];
  const float* w2     = (const float*)d_in[3];
  const float* b      = (const float*)d_in[4];
  const int*   flat   = (const int*)d_in[5];
  float* out = (float*)d_out;

  char* ws = (char*)d_ws;
  unsigned short* xbex = (unsigned short*)(ws);                  // 4096x4352 bf16
  unsigned short* w1b  = (unsigned short*)(ws + 35651584);       // 2 MiB
  unsigned short* w2b  = (unsigned short*)(ws + 37748736);       // 2 MiB (w2all base)
  unsigned short* weff = (unsigned short*)(ws + 39845888);       // 10 MiB (= w2b + 16 panels)
  float*          t1p  = (float*)(ws + 50331648);                // 2 x 4 MiB f32

  cvt_all_kernel<<<2048, 256, 0, stream>>>(x, w1, w2, xbex, w1b, w2b);
  build_weff_kernel<<<5120, 256, 0, stream>>>(weight, flat, weff);
  t1_gemm_kernel<<<dim3(64, 4, 2), 256, 0, stream>>>(xbex, w1b, t1p);
  t1_reduce_kernel<<<4096, 256, 0, stream>>>(t1p, xbex);
  main_gemm_kernel<<<256, 512, 0, stream>>>(xbex, w2b, flat, b, out);
}

// Round 4
// 220.901 us; speedup vs baseline: 1.1593x; 1.1475x over previous
//
#include <hip/hip_runtime.h>
#include <stdint.h>

typedef __bf16 bf16x8 __attribute__((ext_vector_type(8)));
typedef float  f32x4  __attribute__((ext_vector_type(4)));
typedef unsigned short u16x8 __attribute__((ext_vector_type(8)));

typedef __attribute__((address_space(3))) void lds_void;
typedef __attribute__((address_space(1))) const void gbl_cvoid;

__device__ __forceinline__ unsigned short f2bf(float f) {
  union { float f; uint32_t u; } v; v.f = f;
  return (unsigned short)((v.u + 0x7FFFu + ((v.u >> 16) & 1u)) >> 16);
}

// ---------------- prep: fused cvt(x,w1,w2) + butterfly weight gather ---------
__global__ void prep_kernel(const float* __restrict__ x,
                            const float* __restrict__ weight,
                            const float* __restrict__ w1,
                            const float* __restrict__ w2,
                            const int* __restrict__ flat,
                            unsigned short* __restrict__ xb,
                            unsigned short* __restrict__ w1b,
                            unsigned short* __restrict__ w2b,
                            unsigned short* __restrict__ weff) {
  const int NX = (4096 * 4096) / 8;   // 2097152
  const int NW = (256 * 4096) / 8;    // 131072
  const int NF = (20480 * 256) / 8;   // 655360
  const int total = NX + 2 * NW + NF;
  for (int i = blockIdx.x * 256 + threadIdx.x; i < total; i += gridDim.x * 256) {
    const float* src;
    unsigned short* dst;
    if (i < NX) {
      src = x + (size_t)i * 8;  dst = xb + (size_t)i * 8;
    } else if (i < NX + NW) {
      int k = i - NX;
      src = w1 + (size_t)k * 8; dst = w1b + (size_t)k * 8;
    } else if (i < NX + 2 * NW) {
      int k = i - NX - NW;
      src = w2 + (size_t)k * 8; dst = w2b + (size_t)k * 8;
    } else {
      int widx = i - NX - 2 * NW;           // 0..655359
      int row = widx >> 5;                  // 0..20479
      int c8 = (widx & 31) << 3;
      int ob = row / 1280;
      int t  = row - ob * 1280;
      int s  = t >> 8;
      int r  = t & 255;
      int f  = flat[ob * 5 + s];
      int q  = f / 5;
      int jj = f - q * 5;
      int k  = (jj << 8) + r;
      int i2 = k / 5;
      int a  = k - i2 * 5;
      src = weight + ((size_t)((q << 8) + i2) * 5 + a) * 256 + c8;
      dst = weff + (size_t)row * 256 + c8;
    }
    f32x4 va = ((const f32x4*)src)[0], vb = ((const f32x4*)src)[1];
    u16x8 o;
    o[0] = f2bf(va[0]); o[1] = f2bf(va[1]); o[2] = f2bf(va[2]); o[3] = f2bf(va[3]);
    o[4] = f2bf(vb[0]); o[5] = f2bf(vb[1]); o[6] = f2bf(vb[2]); o[7] = f2bf(vb[3]);
    *(u16x8*)dst = o;
  }
}

// ---------------- t1 = x @ w1^T, split-K x2, counted-vmcnt 2-deep dbuf -------
__global__ __launch_bounds__(256) void t1_gemm_kernel(
    const unsigned short* __restrict__ xb,
    const unsigned short* __restrict__ w1b,
    float* __restrict__ t1p) {
  __shared__ __align__(16) char smem[32768];  // dbuf x (A 8K + B 8K)
  const int tid = threadIdx.x, lane = tid & 63, w = tid >> 6;
  const int wr = w >> 1, wc = w & 1;
  const int lr = lane & 15, lk = lane >> 4, lr7 = lr & 7;
  const int row0 = blockIdx.x << 6, col0 = blockIdx.y << 6;
  const int z = blockIdx.z;
  const int rr = tid >> 3;
  const int csw = (tid & 7) ^ (rr & 7);
  const int cs0 = (lk ^ lr7) << 4, cs1 = ((4 | lk) ^ lr7) << 4;
  const int aRow = ((wr << 5) + lr) << 7;
  const int bRow = ((wc << 5) + lr) << 7;

  const unsigned short* As = xb  + (size_t)(row0 + rr) * 4096 + (z << 11) + csw * 8;
  const unsigned short* Bs = w1b + (size_t)(col0 + rr) * 4096 + (z << 11) + csw * 8;

  f32x4 acc[2][2];
#pragma unroll
  for (int m = 0; m < 2; ++m)
#pragma unroll
    for (int n = 0; n < 2; ++n) acc[m][n] = (f32x4){0.f, 0.f, 0.f, 0.f};

  auto STAGE = [&](int t) {
    char* d = smem + ((t & 1) << 14) + (tid << 4);
    const unsigned short* a = As + (t << 6);
    const unsigned short* bp = Bs + (t << 6);
    __builtin_amdgcn_global_load_lds((gbl_cvoid*)a, (lds_void*)d, 16, 0, 0);
    __builtin_amdgcn_global_load_lds((gbl_cvoid*)(a + (size_t)32 * 4096), (lds_void*)(d + 4096), 16, 0, 0);
    __builtin_amdgcn_global_load_lds((gbl_cvoid*)bp, (lds_void*)(d + 8192), 16, 0, 0);
    __builtin_amdgcn_global_load_lds((gbl_cvoid*)(bp + (size_t)32 * 4096), (lds_void*)(d + 12288), 16, 0, 0);
  };

  STAGE(0);
#pragma unroll 1
  for (int t = 0; t < 32; ++t) {
    if (t < 31) {
      STAGE(t + 1);
      asm volatile("s_waitcnt vmcnt(4)" ::: "memory");   // stage(t) landed
    } else {
      asm volatile("s_waitcnt vmcnt(0)" ::: "memory");
    }
    __builtin_amdgcn_s_barrier();
    const char* Ab = smem + ((t & 1) << 14);
    const char* Bb = Ab + 8192;
    bf16x8 aq[2][2], bq[2][2];
#pragma unroll
    for (int m = 0; m < 2; ++m) {
      aq[m][0] = *(const bf16x8*)(Ab + aRow + m * 2048 + cs0);
      aq[m][1] = *(const bf16x8*)(Ab + aRow + m * 2048 + cs1);
      bq[m][0] = *(const bf16x8*)(Bb + bRow + m * 2048 + cs0);
      bq[m][1] = *(const bf16x8*)(Bb + bRow + m * 2048 + cs1);
    }
#pragma unroll
    for (int m = 0; m < 2; ++m)
#pragma unroll
      for (int n = 0; n < 2; ++n) {
        acc[m][n] = __builtin_amdgcn_mfma_f32_16x16x32_bf16(aq[m][0], bq[n][0], acc[m][n], 0, 0, 0);
        acc[m][n] = __builtin_amdgcn_mfma_f32_16x16x32_bf16(aq[m][1], bq[n][1], acc[m][n], 0, 0, 0);
      }
    __builtin_amdgcn_s_barrier();
  }
#pragma unroll
  for (int m = 0; m < 2; ++m)
#pragma unroll
    for (int n = 0; n < 2; ++n) {
      int row = row0 + (wr << 5) + (m << 4) + (lk << 2);
      int col = col0 + (wc << 5) + (n << 4) + lr;
#pragma unroll
      for (int jj = 0; jj < 4; ++jj)
        t1p[((size_t)z << 20) + (size_t)(row + jj) * 256 + col] = acc[m][n][jj];
    }
}

// ---------------- reduce split-K partials -> bf16 t1 [4096][256] -------------
__global__ void t1_reduce_kernel(const float* __restrict__ t1p,
                                 unsigned short* __restrict__ t1) {
  int i = blockIdx.x * 256 + threadIdx.x;   // 1M
  t1[i] = f2bf(t1p[i] + t1p[i + (1 << 20)]);
}

// ---------------- main: BM=256 x BN=128, 4 waves of 128x64, 2-phase ----------
// K-panels: s=0 lowrank (A=t1 stride 256, B=w2b), s=1..5 butterfly
// (A=xb cols q*256, B=weff). 24 K-steps of 64. Single 48KB LDS buffer.
__global__ __launch_bounds__(256, 2) void main_gemm_kernel(
    const unsigned short* __restrict__ xb,
    const unsigned short* __restrict__ t1,
    const unsigned short* __restrict__ w2b,
    const unsigned short* __restrict__ weff,
    const int* __restrict__ flat,
    const float* __restrict__ bias,
    float* __restrict__ out) {
  __shared__ __align__(16) char smem[49152];  // A 32KB | B 16KB
  const int tid  = threadIdx.x;
  const int lane = tid & 63;
  const int w    = tid >> 6;
  const int wr   = w >> 1, wc = w & 1;        // wave = 128 rows x 64 cols
  const int lr   = lane & 15, lk = lane >> 4, lr7 = lr & 7;

  int bid = blockIdx.x;
  int swz = ((bid & 7) << 6) | (bid >> 3);    // bijective: 512 % 8 == 0
  const int bx = swz >> 5, by = swz & 31;     // bx 0..15 (256-row), by 0..31 (128-col)
  const int row0 = bx << 8, col0 = by << 7;
  const int ob = by >> 1, half = by & 1;

  const int cs0 = (lk ^ lr7) << 4;
  const int cs1 = ((4 | lk) ^ lr7) << 4;
  const int aRow = ((wr << 7) + lr) << 7;     // (wr*128+lr)*128 bytes
  const int bRow = ((wc << 6) + lr) << 7;     // (wc*64+lr)*128 bytes

  const int rr = tid >> 3;                    // 0..31
  const int csw = (tid & 7) ^ (rr & 7);

  const int base5 = ob * 5;
  const int cA1 = (flat[base5 + 0] / 5) << 8;
  const int cA2 = (flat[base5 + 1] / 5) << 8;
  const int cA3 = (flat[base5 + 2] / 5) << 8;
  const int cA4 = (flat[base5 + 3] / 5) << 8;
  const int cA5 = (flat[base5 + 4] / 5) << 8;

  f32x4 acc[8][4];
#pragma unroll
  for (int m = 0; m < 8; ++m)
#pragma unroll
    for (int n = 0; n < 4; ++n) acc[m][n] = (f32x4){0.f, 0.f, 0.f, 0.f};

#pragma unroll 1
  for (int st = 0; st < 24; ++st) {
    int s = st >> 2, k0 = (st & 3) << 6;
    // A source: stride 256 (t1) or 4096 (xb panel)
    const unsigned short* Abase;
    int Astr;
    if (s == 0) { Abase = t1 + (size_t)row0 * 256; Astr = 256; }
    else {
      int colA = (s == 1) ? cA1 : (s == 2) ? cA2 : (s == 3) ? cA3
               : (s == 4) ? cA4 : cA5;
      Abase = xb + (size_t)row0 * 4096 + colA; Astr = 4096;
    }
    const unsigned short* Bbase = (s == 0)
        ? (w2b + (size_t)col0 * 256)
        : (weff + ((size_t)(base5 + s - 1) * 256 + (half << 7)) * 256);

    // stage A (2048 chunks) + B (1024 chunks)
#pragma unroll
    for (int it = 0; it < 8; ++it) {
      int r = (it << 5) + rr;
      const unsigned short* srcA = Abase + (size_t)r * Astr + k0 + csw * 8;
      __builtin_amdgcn_global_load_lds((gbl_cvoid*)srcA,
          (lds_void*)&smem[(it << 12) + (tid << 4)], 16, 0, 0);
    }
#pragma unroll
    for (int it = 0; it < 4; ++it) {
      int r = (it << 5) + rr;
      const unsigned short* srcB = Bbase + (size_t)r * 256 + k0 + csw * 8;
      __builtin_amdgcn_global_load_lds((gbl_cvoid*)srcB,
          (lds_void*)&smem[32768 + (it << 12) + (tid << 4)], 16, 0, 0);
    }
    asm volatile("s_waitcnt vmcnt(0)" ::: "memory");
    __builtin_amdgcn_s_barrier();

#pragma unroll
    for (int kk = 0; kk < 2; ++kk) {
      int cs = (kk == 0) ? cs0 : cs1;
      bf16x8 bq[4];
#pragma unroll
      for (int n = 0; n < 4; ++n)
        bq[n] = *(const bf16x8*)(smem + 32768 + bRow + n * 2048 + cs);
#pragma unroll
      for (int m = 0; m < 8; ++m) {
        bf16x8 aqm = *(const bf16x8*)(smem + aRow + m * 2048 + cs);
#pragma unroll
        for (int n = 0; n < 4; ++n)
          acc[m][n] = __builtin_amdgcn_mfma_f32_16x16x32_bf16(
              aqm, bq[n], acc[m][n], 0, 0, 0);
      }
    }
    __builtin_amdgcn_s_barrier();
  }

  // epilogue: + bias, f32 store
#pragma unroll
  for (int n = 0; n < 4; ++n) {
    int col = col0 + (wc << 6) + (n << 4) + lr;
    float bv = bias[col];
#pragma unroll
    for (int m = 0; m < 8; ++m) {
      int row = row0 + (wr << 7) + (m << 4) + (lk << 2);
#pragma unroll
      for (int jj = 0; jj < 4; ++jj)
        out[(size_t)(row + jj) * 4096 + col] = acc[m][n][jj] + bv;
    }
  }
}

extern "C" void kernel_launch(void* const* d_in, const int* in_sizes, int n_in,
                              void* d_out, int out_size, void* d_ws, size_t ws_size,
                              hipStream_t stream) {
  const float* x      = (const float*)d_in[0];
  const float* weight = (const float*)d_in[1];
  const float* w1     = (const float*)d_in[2];
  const float* w2     = (const float*)d_in[3];
  const float* b      = (const float*)d_in[4];
  const int*   flat   = (const int*)d_in[5];
  float* out = (float*)d_out;

  char* ws = (char*)d_ws;
  unsigned short* xb   = (unsigned short*)(ws);                  // 32 MiB
  unsigned short* w1b  = (unsigned short*)(ws + 33554432);       // 2 MiB
  unsigned short* w2b  = (unsigned short*)(ws + 35651584);       // 2 MiB
  unsigned short* weff = (unsigned short*)(ws + 37748736);       // 10 MiB
  unsigned short* t1   = (unsigned short*)(ws + 48234496);       // 2 MiB
  float*          t1p  = (float*)(ws + 50331648);                // 8 MiB

  prep_kernel<<<2048, 256, 0, stream>>>(x, weight, w1, w2, flat, xb, w1b, w2b, weff);
  t1_gemm_kernel<<<dim3(64, 4, 2), 256, 0, stream>>>(xb, w1b, t1p);
  t1_reduce_kernel<<<4096, 256, 0, stream>>>(t1p, t1);
  main_gemm_kernel<<<512, 256, 0, stream>>>(xb, t1, w2b, weff, flat, b, out);
}